// Round 2
// baseline (949.233 us; speedup 1.0000x reference)
//
#include <hip/hip_runtime.h>

#define HH 512
#define WW 512
#define HWC (HH * WW)          // 262144 = 2^18
#define NV 50000
#define NB 4

static __device__ __forceinline__ float4 ld4(const float* p) {
    return *reinterpret_cast<const float4*>(p);
}

// ---------------------------------------------------------------------------
// K1: scatter voxel indices into dense coord->index grids
// grids layout: [set(0=li,1=ra)][b][HWC], pre-filled with -1
// ---------------------------------------------------------------------------
__global__ void k_grid(const int* __restrict__ li_coors, const int* __restrict__ ra_coors,
                       int* __restrict__ grids) {
    int t = blockIdx.x * blockDim.x + threadIdx.x;
    if (t >= 2 * NB * NV) return;
    int set = t / (NB * NV);
    int r2 = t - set * (NB * NV);
    int b = r2 / NV;
    int n = r2 - b * NV;
    const int* co = (set == 0 ? li_coors : ra_coors) + (size_t)(b * NV + n) * 2;
    grids[(set * NB + b) * HWC + co[0] * WW + co[1]] = n;
}

// ---------------------------------------------------------------------------
// K2: pre-project K,V for every kv row of both branches.
// KV layout: [br][b][n][64]  (0..31 = K row, 32..63 = V row)
// ---------------------------------------------------------------------------
__launch_bounds__(256)
__global__ void k_proj(const float* __restrict__ li_feats, const float* __restrict__ ra_feats,
                       const float* __restrict__ w_qkv1, const float* __restrict__ b_qkv1,
                       const float* __restrict__ w_qkv2, const float* __restrict__ b_qkv2,
                       float* __restrict__ KV) {
    const int br   = blockIdx.x & 1;
    const int lane = threadIdx.x & 63;
    const int j    = lane & 31;
    const int half = lane >> 5;  // 0 = K, 1 = V
    const float* wqkv = br ? w_qkv2 : w_qkv1;
    const float* bqkv = br ? b_qkv2 : b_qkv1;
    const float* kvf  = br ? li_feats : ra_feats;
    const int wrow = 32 + half * 32 + j;  // wk rows 32..63, wv rows 64..95
    float4 wr[8];
#pragma unroll
    for (int i = 0; i < 8; ++i) wr[i] = ld4(wqkv + wrow * 32 + i * 4);
    const float bias = bqkv[wrow];

    int wave   = (blockIdx.x >> 1) * (blockDim.x >> 6) + (threadIdx.x >> 6);
    int stride = (gridDim.x >> 1) * (blockDim.x >> 6);
    float* KVb = KV + (size_t)br * NB * NV * 64;
    for (int row = wave; row < NB * NV; row += stride) {
        const float* rp = kvf + (size_t)row * 32;
        float acc = bias;
#pragma unroll
        for (int i = 0; i < 8; ++i) {
            float4 rv = ld4(rp + i * 4);
            float4 w = wr[i];
            acc += w.x * rv.x + w.y * rv.y + w.z * rv.z + w.w * rv.w;
        }
        KVb[(size_t)row * 64 + lane] = acc;
    }
}

// ---------------------------------------------------------------------------
// K3: fused per-query attention, 2 queries per 32-lane group (ILP x2).
// Branchless gathers, batch-issued loads, no __syncthreads (intra-wave LDS).
// res layout: [br][b][n][32] = q_feat + attn_out
// ---------------------------------------------------------------------------
__launch_bounds__(256, 4)
__global__ void k_attn(const float* __restrict__ li_feats, const float* __restrict__ ra_feats,
                       const int* __restrict__ li_coors, const int* __restrict__ ra_coors,
                       const float* __restrict__ w_qkv1, const float* __restrict__ b_qkv1,
                       const float* __restrict__ w_out1, const float* __restrict__ b_out1,
                       const float* __restrict__ w_qkv2, const float* __restrict__ b_qkv2,
                       const float* __restrict__ w_out2, const float* __restrict__ b_out2,
                       const int* __restrict__ grids, const float* __restrict__ KV,
                       float* __restrict__ res) {
    __shared__ float q_lds[8][2][32];
    __shared__ float o_lds[8][2][32];
    const int g = threadIdx.x >> 5;
    const int j = threadIdx.x & 31;
    const int qp = blockIdx.x * 8 + g;       // pair id, 0 .. NB*NV - 1
    const int q0 = qp * 2;                   // pairs never straddle b or br
    const int br  = (q0 >= NB * NV) ? 1 : 0;
    const int rem = q0 - br * NB * NV;
    const int b   = rem / NV;
    const int n0  = rem - b * NV;

    const float* qf   = br ? ra_feats : li_feats;
    const int*   qc   = br ? ra_coors : li_coors;
    const float* wqkv = br ? w_qkv2 : w_qkv1;
    const float* bqkv = br ? b_qkv2 : b_qkv1;
    const float* wout = br ? w_out2 : w_out1;
    const float* bout = br ? b_out2 : b_out1;
    const int* kvgrid = grids + ((br == 0 ? 1 : 0) * NB + b) * HWC;
    const float* KVb  = KV + ((size_t)br * NB + b) * (size_t)NV * 64;

    // ---- stage 0: coords (issue first) --------------------------------
    int r0[2], c0[2];
#pragma unroll
    for (int u = 0; u < 2; ++u) {
        r0[u] = qc[(size_t)(b * NV + n0 + u) * 2];
        c0[u] = qc[(size_t)(b * NV + n0 + u) * 2 + 1];
    }

    const int drs[9] = {0, -1, 1, 0, -1, 1, 0, -1, 1};
    const int dcs[9] = {0, 0, 0, 1, 1, 1, -1, -1, -1};

    // ---- stage 1: 18 branchless grid loads ----------------------------
    int idx[2][9];
#pragma unroll
    for (int u = 0; u < 2; ++u)
#pragma unroll
        for (int k = 0; k < 9; ++k) {
            int rr = r0[u] + drs[k], cc = c0[u] + dcs[k];
            bool valid = ((unsigned)rr < HH) & ((unsigned)cc < WW);
            int flat = valid ? rr * WW + cc : 0;
            int raw = kvgrid[flat];
            idx[u][k] = valid ? raw : -1;
        }

    // ---- stage 2: q rows, weights (hide grid-load latency) ------------
    float qv[2];
#pragma unroll
    for (int u = 0; u < 2; ++u) {
        qv[u] = qf[(size_t)(b * NV + n0 + u) * 32 + j];
        q_lds[g][u][j] = qv[u];
    }
    float4 wqr[8], wor[8];
#pragma unroll
    for (int i = 0; i < 8; ++i) {
        wqr[i] = ld4(wqkv + j * 32 + i * 4);
        wor[i] = ld4(wout + j * 32 + i * 4);
    }
    const float bq = bqkv[j], bk = bqkv[32 + j], bv = bqkv[64 + j], bo = bout[j];

    // ---- stage 3: Q projection (VALU while grid loads land) -----------
    float Q[2] = {bq, bq};
#pragma unroll
    for (int i = 0; i < 8; ++i) {
        float4 w = wqr[i];
#pragma unroll
        for (int u = 0; u < 2; ++u) {
            float4 qd = *reinterpret_cast<const float4*>(&q_lds[g][u][i * 4]);
            Q[u] += w.x * qd.x + w.y * qd.y + w.z * qd.z + w.w * qd.w;
        }
    }

    // ---- stage 4: 36 branchless KV loads ------------------------------
    float Kv[2][9], Vx[2][9];
    int fnd[2] = {0, 0};
#pragma unroll
    for (int u = 0; u < 2; ++u)
#pragma unroll
        for (int k = 0; k < 9; ++k) {
            int ic = idx[u][k] > 0 ? idx[u][k] : 0;
            const float* kvp = KVb + (size_t)ic * 64;
            Kv[u][k] = kvp[j];
            Vx[u][k] = kvp[32 + j];
            fnd[u] |= (idx[u][k] >= 0) << k;
        }

    // ---- stage 5: scores ----------------------------------------------
    float sc[2][9];
#pragma unroll
    for (int u = 0; u < 2; ++u)
#pragma unroll
        for (int k = 0; k < 9; ++k) {
            float kk = ((fnd[u] >> k) & 1) ? Kv[u][k] : bk;
            float p = Q[u] * kk;
            p += __shfl_xor(p, 1, 16);
            p += __shfl_xor(p, 2, 16);
            p += __shfl_xor(p, 4, 16);
            p += __shfl_xor(p, 8, 16);
            sc[u][k] = p * 0.25f;  // 1/sqrt(HD=16)
        }

    // ---- stage 6: softmax + weighted V + out-proj ---------------------
#pragma unroll
    for (int u = 0; u < 2; ++u) {
        float m = sc[u][0];
#pragma unroll
        for (int k = 1; k < 9; ++k) m = fmaxf(m, sc[u][k]);
        float sum = 0.f, o = 0.f;
#pragma unroll
        for (int k = 0; k < 9; ++k) {
            float e = __expf(sc[u][k] - m);
            float vv = ((fnd[u] >> k) & 1) ? Vx[u][k] : bv;
            sum += e;
            o += e * vv;
        }
        o_lds[g][u][j] = o / sum;
    }

    float outv[2] = {bo, bo};
#pragma unroll
    for (int i = 0; i < 8; ++i) {
        float4 w = wor[i];
#pragma unroll
        for (int u = 0; u < 2; ++u) {
            float4 od = *reinterpret_cast<const float4*>(&o_lds[g][u][i * 4]);
            outv[u] += w.x * od.x + w.y * od.y + w.z * od.z + w.w * od.w;
        }
    }
#pragma unroll
    for (int u = 0; u < 2; ++u)
        res[(size_t)(q0 + u) * 32 + j] = qv[u] + outv[u];
}

// ---------------------------------------------------------------------------
// K4: densify (inverted scatter). One thread per output cell; writes all 32
// channel planes coalesced, gathers the 128B res row (or zeros).
// ---------------------------------------------------------------------------
__launch_bounds__(256)
__global__ void k_densify(const int* __restrict__ grids, const float* __restrict__ res,
                          float* __restrict__ out) {
    int t = blockIdx.x * 256 + threadIdx.x;  // 0 .. 2*NB*HWC-1
    int plane = t >> 18;                     // (br*NB + b)
    int s = t & (HWC - 1);
    int gidx = grids[t];                     // query grid (set==branch)
    float4 v[8];
    if (gidx >= 0) {
        const float* rp = res + ((size_t)plane * NV + gidx) * 32;
#pragma unroll
        for (int i = 0; i < 8; ++i) v[i] = ld4(rp + i * 4);
    } else {
#pragma unroll
        for (int i = 0; i < 8; ++i) v[i] = make_float4(0.f, 0.f, 0.f, 0.f);
    }
    float* ob = out + (size_t)plane * 32 * HWC + s;
#pragma unroll
    for (int i = 0; i < 8; ++i) {
        ob[(size_t)(4 * i + 0) * HWC] = v[i].x;
        ob[(size_t)(4 * i + 1) * HWC] = v[i].y;
        ob[(size_t)(4 * i + 2) * HWC] = v[i].z;
        ob[(size_t)(4 * i + 3) * HWC] = v[i].w;
    }
}

// ---------------------------------------------------------------------------
extern "C" void kernel_launch(void* const* d_in, const int* in_sizes, int n_in,
                              void* d_out, int out_size, void* d_ws, size_t ws_size,
                              hipStream_t stream) {
    const float* li_feats = (const float*)d_in[0];
    const int*   li_coors = (const int*)d_in[1];
    const float* ra_feats = (const float*)d_in[2];
    const int*   ra_coors = (const int*)d_in[3];
    const float* w_qkv1 = (const float*)d_in[4];
    const float* b_qkv1 = (const float*)d_in[5];
    const float* w_out1 = (const float*)d_in[6];
    const float* b_out1 = (const float*)d_in[7];
    const float* w_qkv2 = (const float*)d_in[8];
    const float* b_qkv2 = (const float*)d_in[9];
    const float* w_out2 = (const float*)d_in[10];
    const float* b_out2 = (const float*)d_in[11];
    float* out = (float*)d_out;

    char* ws = (char*)d_ws;
    int*   grids = (int*)ws;                                        // 8 MB
    float* KV    = (float*)(ws + (size_t)2 * NB * HWC * 4);         // 102.4 MB
    float* res   = (float*)(ws + (size_t)2 * NB * HWC * 4
                               + (size_t)2 * NB * NV * 64 * 4);     // 51.2 MB

    hipMemsetAsync(grids, 0xFF, (size_t)2 * NB * HWC * 4, stream);  // all -1

    k_grid<<<(2 * NB * NV + 255) / 256, 256, 0, stream>>>(li_coors, ra_coors, grids);

    k_proj<<<1024, 256, 0, stream>>>(li_feats, ra_feats,
                                     w_qkv1, b_qkv1, w_qkv2, b_qkv2, KV);

    k_attn<<<(NB * NV) / 8, 256, 0, stream>>>(
        li_feats, ra_feats, li_coors, ra_coors,
        w_qkv1, b_qkv1, w_out1, b_out1,
        w_qkv2, b_qkv2, w_out2, b_out2,
        grids, KV, res);

    k_densify<<<(2 * NB * HWC) / 256, 256, 0, stream>>>(grids, res, out);
}

// Round 3
// 693.216 us; speedup vs baseline: 1.3693x; 1.3693x over previous
//
#include <hip/hip_runtime.h>

#define HH 512
#define WW 512
#define HWC (HH * WW)          // 262144 = 2^18
#define NV 50000
#define NB 4

static __device__ __forceinline__ float4 ld4(const float* p) {
    return *reinterpret_cast<const float4*>(p);
}

// Sum across each 16-lane row via DPP (VALU pipe, no LDS).
static __device__ __forceinline__ float red16(float x) {
    float t;
    t = __int_as_float(__builtin_amdgcn_update_dpp(0, __float_as_int(x), 0xB1, 0xF, 0xF, true));  // quad_perm(1,0,3,2)
    x += t;
    t = __int_as_float(__builtin_amdgcn_update_dpp(0, __float_as_int(x), 0x4E, 0xF, 0xF, true));  // quad_perm(2,3,0,1)
    x += t;
    t = __int_as_float(__builtin_amdgcn_update_dpp(0, __float_as_int(x), 0x141, 0xF, 0xF, true)); // row_half_mirror
    x += t;
    t = __int_as_float(__builtin_amdgcn_update_dpp(0, __float_as_int(x), 0x140, 0xF, 0xF, true)); // row_mirror
    x += t;
    return x;
}

// ---------------------------------------------------------------------------
// K1: scatter voxel indices into dense coord->index grids
// grids layout: [set(0=li,1=ra)][b][HWC], pre-filled with -1
// ---------------------------------------------------------------------------
__global__ void k_grid(const int* __restrict__ li_coors, const int* __restrict__ ra_coors,
                       int* __restrict__ grids) {
    int t = blockIdx.x * blockDim.x + threadIdx.x;
    if (t >= 2 * NB * NV) return;
    int set = t / (NB * NV);
    int r2 = t - set * (NB * NV);
    int b = r2 / NV;
    int n = r2 - b * NV;
    const int* co = (set == 0 ? li_coors : ra_coors) + (size_t)(b * NV + n) * 2;
    grids[(set * NB + b) * HWC + co[0] * WW + co[1]] = n;
}

// ---------------------------------------------------------------------------
// K2: pre-project K,V for every kv row of both branches.
// KV layout: [br][b][n][j][2]  ([0]=K_j, [1]=V_j) -> one float2 per gather.
// branch 0: kv = ra_feats with w_qkv1 ; branch 1: kv = li_feats with w_qkv2
// ---------------------------------------------------------------------------
__launch_bounds__(256)
__global__ void k_proj(const float* __restrict__ li_feats, const float* __restrict__ ra_feats,
                       const float* __restrict__ w_qkv1, const float* __restrict__ b_qkv1,
                       const float* __restrict__ w_qkv2, const float* __restrict__ b_qkv2,
                       float* __restrict__ KV) {
    const int br   = blockIdx.x & 1;
    const int lane = threadIdx.x & 63;
    const int j    = lane & 31;
    const int half = lane >> 5;  // 0 = K, 1 = V
    const float* wqkv = br ? w_qkv2 : w_qkv1;
    const float* bqkv = br ? b_qkv2 : b_qkv1;
    const float* kvf  = br ? li_feats : ra_feats;
    const int wrow = 32 + half * 32 + j;  // wk rows 32..63, wv rows 64..95
    float4 wr[8];
#pragma unroll
    for (int i = 0; i < 8; ++i) wr[i] = ld4(wqkv + wrow * 32 + i * 4);
    const float bias = bqkv[wrow];

    int wave   = (blockIdx.x >> 1) * (blockDim.x >> 6) + (threadIdx.x >> 6);
    int stride = (gridDim.x >> 1) * (blockDim.x >> 6);
    float* KVb = KV + (size_t)br * NB * NV * 64;
    for (int row = wave; row < NB * NV; row += stride) {
        const float* rp = kvf + (size_t)row * 32;
        float acc = bias;
#pragma unroll
        for (int i = 0; i < 8; ++i) {
            float4 rv = ld4(rp + i * 4);
            float4 w = wr[i];
            acc += w.x * rv.x + w.y * rv.y + w.z * rv.z + w.w * rv.w;
        }
        KVb[(size_t)row * 64 + j * 2 + half] = acc;
    }
}

// ---------------------------------------------------------------------------
// K3: fused per-query attention. 32 lanes per query, 8 queries/block.
// Branchless batched gathers, float2 K|V, DPP score reduce, no __syncthreads.
// res layout: [br][b][n][32] = q_feat + attn_out
// ---------------------------------------------------------------------------
__launch_bounds__(256)
__global__ void k_attn(const float* __restrict__ li_feats, const float* __restrict__ ra_feats,
                       const int* __restrict__ li_coors, const int* __restrict__ ra_coors,
                       const float* __restrict__ w_qkv1, const float* __restrict__ b_qkv1,
                       const float* __restrict__ w_out1, const float* __restrict__ b_out1,
                       const float* __restrict__ w_qkv2, const float* __restrict__ b_qkv2,
                       const float* __restrict__ w_out2, const float* __restrict__ b_out2,
                       const int* __restrict__ grids, const float* __restrict__ KV,
                       float* __restrict__ res) {
    __shared__ float o_lds[8][32];
    const int g = threadIdx.x >> 5;
    const int j = threadIdx.x & 31;
    const int qid = blockIdx.x * 8 + g;
    const int br  = (qid >= NB * NV) ? 1 : 0;
    const int rem = qid - br * NB * NV;
    const int b   = rem / NV;
    const int n   = rem - b * NV;

    const float* qf   = br ? ra_feats : li_feats;
    const int*   qc   = br ? ra_coors : li_coors;
    const float* wqkv = br ? w_qkv2 : w_qkv1;
    const float* bqkv = br ? b_qkv2 : b_qkv1;
    const float* wout = br ? w_out2 : w_out1;
    const float* bout = br ? b_out2 : b_out1;
    const int* kvgrid = grids + ((br == 0 ? 1 : 0) * NB + b) * HWC;
    const float* KVb  = KV + ((size_t)br * NB + b) * (size_t)NV * 64;

    // ---- stage 0: coords (one int2 load, issued first) ----------------
    const int2 rc = *reinterpret_cast<const int2*>(qc + (size_t)(b * NV + n) * 2);

    const int drs[9] = {0, -1, 1, 0, -1, 1, 0, -1, 1};
    const int dcs[9] = {0, 0, 0, 1, 1, 1, -1, -1, -1};

    // ---- stage 1: 9 branchless grid loads (batched) --------------------
    int idx[9];
#pragma unroll
    for (int k = 0; k < 9; ++k) {
        int rr = rc.x + drs[k], cc = rc.y + dcs[k];
        bool valid = ((unsigned)rr < HH) & ((unsigned)cc < WW);
        int raw = kvgrid[valid ? rr * WW + cc : 0];
        idx[k] = valid ? raw : -1;
    }

    // ---- stage 2: Q projection via broadcast global reads --------------
    const float* qrow = qf + (size_t)(b * NV + n) * 32;
    const float qv = qrow[j];
    float Q = bqkv[j];
#pragma unroll
    for (int i = 0; i < 8; ++i) {
        float4 w  = ld4(wqkv + j * 32 + i * 4);
        float4 qd = ld4(qrow + i * 4);           // all lanes same addr: broadcast
        Q += w.x * qd.x + w.y * qd.y + w.z * qd.z + w.w * qd.w;
    }

    // ---- stage 3: 9 batched float2 K|V gathers --------------------------
    float2 kv[9];
    unsigned fnd = 0;
#pragma unroll
    for (int k = 0; k < 9; ++k) {
        int ic = idx[k] > 0 ? idx[k] : 0;
        kv[k] = *reinterpret_cast<const float2*>(KVb + (size_t)ic * 64 + j * 2);
        fnd |= (unsigned)(idx[k] >= 0) << k;
    }
    const float bk = bqkv[32 + j], bv = bqkv[64 + j];

    // ---- stage 4: scores (DPP reduce over 16-lane heads) ----------------
    float sc[9];
#pragma unroll
    for (int k = 0; k < 9; ++k) {
        float kk = ((fnd >> k) & 1) ? kv[k].x : bk;
        sc[k] = red16(Q * kk) * 0.25f;  // 1/sqrt(HD=16)
    }

    // ---- stage 5: softmax + weighted V -----------------------------------
    float m = sc[0];
#pragma unroll
    for (int k = 1; k < 9; ++k) m = fmaxf(m, sc[k]);
    float sum = 0.f, o = 0.f;
#pragma unroll
    for (int k = 0; k < 9; ++k) {
        float e = __expf(sc[k] - m);
        float vv = ((fnd >> k) & 1) ? kv[k].y : bv;
        sum += e;
        o += e * vv;
    }
    o_lds[g][j] = o / sum;   // intra-wave producer/consumer: no barrier needed

    // ---- stage 6: out-projection (weights loaded late; K/V regs dead) ---
    float outv = bout[j];
#pragma unroll
    for (int i = 0; i < 8; ++i) {
        float4 w  = ld4(wout + j * 32 + i * 4);
        float4 od = *reinterpret_cast<const float4*>(&o_lds[g][i * 4]);
        outv += w.x * od.x + w.y * od.y + w.z * od.z + w.w * od.w;
    }
    res[(size_t)qid * 32 + j] = qv + outv;
}

// ---------------------------------------------------------------------------
// K4: densify (inverted scatter). One thread per output cell; writes all 32
// channel planes coalesced, gathers the 128B res row (or zeros).
// ---------------------------------------------------------------------------
__launch_bounds__(256)
__global__ void k_densify(const int* __restrict__ grids, const float* __restrict__ res,
                          float* __restrict__ out) {
    int t = blockIdx.x * 256 + threadIdx.x;  // 0 .. 2*NB*HWC-1
    int plane = t >> 18;                     // (br*NB + b)
    int s = t & (HWC - 1);
    int gidx = grids[t];                     // query grid (set==branch)
    float4 v[8];
    if (gidx >= 0) {
        const float* rp = res + ((size_t)plane * NV + gidx) * 32;
#pragma unroll
        for (int i = 0; i < 8; ++i) v[i] = ld4(rp + i * 4);
    } else {
#pragma unroll
        for (int i = 0; i < 8; ++i) v[i] = make_float4(0.f, 0.f, 0.f, 0.f);
    }
    float* ob = out + (size_t)plane * 32 * HWC + s;
#pragma unroll
    for (int i = 0; i < 8; ++i) {
        ob[(size_t)(4 * i + 0) * HWC] = v[i].x;
        ob[(size_t)(4 * i + 1) * HWC] = v[i].y;
        ob[(size_t)(4 * i + 2) * HWC] = v[i].z;
        ob[(size_t)(4 * i + 3) * HWC] = v[i].w;
    }
}

// ---------------------------------------------------------------------------
extern "C" void kernel_launch(void* const* d_in, const int* in_sizes, int n_in,
                              void* d_out, int out_size, void* d_ws, size_t ws_size,
                              hipStream_t stream) {
    const float* li_feats = (const float*)d_in[0];
    const int*   li_coors = (const int*)d_in[1];
    const float* ra_feats = (const float*)d_in[2];
    const int*   ra_coors = (const int*)d_in[3];
    const float* w_qkv1 = (const float*)d_in[4];
    const float* b_qkv1 = (const float*)d_in[5];
    const float* w_out1 = (const float*)d_in[6];
    const float* b_out1 = (const float*)d_in[7];
    const float* w_qkv2 = (const float*)d_in[8];
    const float* b_qkv2 = (const float*)d_in[9];
    const float* w_out2 = (const float*)d_in[10];
    const float* b_out2 = (const float*)d_in[11];
    float* out = (float*)d_out;

    char* ws = (char*)d_ws;
    int*   grids = (int*)ws;                                        // 8 MB
    float* KV    = (float*)(ws + (size_t)2 * NB * HWC * 4);         // 102.4 MB
    float* res   = (float*)(ws + (size_t)2 * NB * HWC * 4
                               + (size_t)2 * NB * NV * 64 * 4);     // 51.2 MB

    hipMemsetAsync(grids, 0xFF, (size_t)2 * NB * HWC * 4, stream);  // all -1

    k_grid<<<(2 * NB * NV + 255) / 256, 256, 0, stream>>>(li_coors, ra_coors, grids);

    k_proj<<<1024, 256, 0, stream>>>(li_feats, ra_feats,
                                     w_qkv1, b_qkv1, w_qkv2, b_qkv2, KV);

    k_attn<<<(2 * NB * NV) / 8, 256, 0, stream>>>(
        li_feats, ra_feats, li_coors, ra_coors,
        w_qkv1, b_qkv1, w_out1, b_out1,
        w_qkv2, b_qkv2, w_out2, b_out2,
        grids, KV, res);

    k_densify<<<(2 * NB * HWC) / 256, 256, 0, stream>>>(grids, res, out);
}

// Round 4
// 477.965 us; speedup vs baseline: 1.9860x; 1.4503x over previous
//
#include <hip/hip_runtime.h>

#define HH 512
#define WW 512
#define HWC (HH * WW)          // 262144 = 2^18
#define NV 50000
#define NB 4
#define NQ (2 * NB * NV)       // 400000 total queries (both branches)

static __device__ __forceinline__ float4 ld4(const float* p) {
    return *reinterpret_cast<const float4*>(p);
}

// Sum across each 16-lane row via DPP (VALU pipe, no LDS).
static __device__ __forceinline__ float red16(float x) {
    float t;
    t = __int_as_float(__builtin_amdgcn_update_dpp(0, __float_as_int(x), 0xB1, 0xF, 0xF, true));  // quad_perm(1,0,3,2)
    x += t;
    t = __int_as_float(__builtin_amdgcn_update_dpp(0, __float_as_int(x), 0x4E, 0xF, 0xF, true));  // quad_perm(2,3,0,1)
    x += t;
    t = __int_as_float(__builtin_amdgcn_update_dpp(0, __float_as_int(x), 0x141, 0xF, 0xF, true)); // row_half_mirror
    x += t;
    t = __int_as_float(__builtin_amdgcn_update_dpp(0, __float_as_int(x), 0x140, 0xF, 0xF, true)); // row_mirror
    x += t;
    return x;
}

// ---------------------------------------------------------------------------
// K1: scatter voxel indices into dense coord->index grids
// grids layout: [set(0=li,1=ra)][b][HWC], pre-filled with -1
// ---------------------------------------------------------------------------
__global__ void k_grid(const int* __restrict__ li_coors, const int* __restrict__ ra_coors,
                       int* __restrict__ grids) {
    int t = blockIdx.x * blockDim.x + threadIdx.x;
    if (t >= NQ) return;
    int set = t / (NB * NV);
    int r2 = t - set * (NB * NV);
    int b = r2 / NV;
    int n = r2 - b * NV;
    const int* co = (set == 0 ? li_coors : ra_coors) + (size_t)(b * NV + n) * 2;
    grids[(set * NB + b) * HWC + co[0] * WW + co[1]] = n;
}

// ---------------------------------------------------------------------------
// K2: pre-project K,V for every kv row of both branches.
// KV layout: [br][b][n][j][2]  ([0]=K_j, [1]=V_j) -> one float2 per gather.
// branch 0: kv = ra_feats with w_qkv1 ; branch 1: kv = li_feats with w_qkv2
// ---------------------------------------------------------------------------
__launch_bounds__(256)
__global__ void k_proj(const float* __restrict__ li_feats, const float* __restrict__ ra_feats,
                       const float* __restrict__ w_qkv1, const float* __restrict__ b_qkv1,
                       const float* __restrict__ w_qkv2, const float* __restrict__ b_qkv2,
                       float* __restrict__ KV) {
    const int br   = blockIdx.x & 1;
    const int lane = threadIdx.x & 63;
    const int j    = lane & 31;
    const int half = lane >> 5;  // 0 = K, 1 = V
    const float* wqkv = br ? w_qkv2 : w_qkv1;
    const float* bqkv = br ? b_qkv2 : b_qkv1;
    const float* kvf  = br ? li_feats : ra_feats;
    const int wrow = 32 + half * 32 + j;  // wk rows 32..63, wv rows 64..95
    float4 wr[8];
#pragma unroll
    for (int i = 0; i < 8; ++i) wr[i] = ld4(wqkv + wrow * 32 + i * 4);
    const float bias = bqkv[wrow];

    int wave   = (blockIdx.x >> 1) * (blockDim.x >> 6) + (threadIdx.x >> 6);
    int stride = (gridDim.x >> 1) * (blockDim.x >> 6);
    float* KVb = KV + (size_t)br * NB * NV * 64;
    for (int row = wave; row < NB * NV; row += stride) {
        const float* rp = kvf + (size_t)row * 32;
        float acc = bias;
#pragma unroll
        for (int i = 0; i < 8; ++i) {
            float4 rv = ld4(rp + i * 4);
            float4 w = wr[i];
            acc += w.x * rv.x + w.y * rv.y + w.z * rv.z + w.w * rv.w;
        }
        KVb[(size_t)row * 64 + j * 2 + half] = acc;
    }
}

// ---------------------------------------------------------------------------
// K2b: pre-project Q for every query row of both branches.
// Qbuf layout: [br][b][n][32]. Wave handles 2 rows (half-wave each).
// ---------------------------------------------------------------------------
__launch_bounds__(256)
__global__ void k_qproj(const float* __restrict__ li_feats, const float* __restrict__ ra_feats,
                        const float* __restrict__ w_qkv1, const float* __restrict__ b_qkv1,
                        const float* __restrict__ w_qkv2, const float* __restrict__ b_qkv2,
                        float* __restrict__ Qbuf) {
    const int br   = blockIdx.x & 1;
    const int lane = threadIdx.x & 63;
    const int j    = lane & 31;
    const int h    = lane >> 5;
    const float* wqkv = br ? w_qkv2 : w_qkv1;
    const float* qf   = br ? ra_feats : li_feats;
    float4 wr[8];
#pragma unroll
    for (int i = 0; i < 8; ++i) wr[i] = ld4(wqkv + j * 32 + i * 4);  // wq row j
    const float bias = (br ? b_qkv2 : b_qkv1)[j];

    int wave   = (blockIdx.x >> 1) * (blockDim.x >> 6) + (threadIdx.x >> 6);
    int stride = (gridDim.x >> 1) * (blockDim.x >> 6);
    float* Qb = Qbuf + (size_t)br * NB * NV * 32;
    for (int pr = wave; pr < NB * NV / 2; pr += stride) {
        int row = pr * 2 + h;
        const float* rp = qf + (size_t)row * 32;
        float acc = bias;
#pragma unroll
        for (int i = 0; i < 8; ++i) {
            float4 rv = ld4(rp + i * 4);
            float4 w = wr[i];
            acc += w.x * rv.x + w.y * rv.y + w.z * rv.z + w.w * rv.w;
        }
        Qb[(size_t)row * 32 + j] = acc;
    }
}

// ---------------------------------------------------------------------------
// K3a: neighbor resolve. 1 thread per query; 9 independent grid loads, huge
// TLP hides L2 latency. Writes [q][12]: idx0..8 (clamped), mask, pad, pad.
// ---------------------------------------------------------------------------
__global__ void k_nbr(const int* __restrict__ li_coors, const int* __restrict__ ra_coors,
                      const int* __restrict__ grids, int* __restrict__ nbr) {
    int q = blockIdx.x * 256 + threadIdx.x;
    if (q >= NQ) return;
    int br  = (q >= NB * NV) ? 1 : 0;
    int rem = q - br * NB * NV;
    int b   = rem / NV;
    int n   = rem - b * NV;
    const int* qc = br ? ra_coors : li_coors;
    const int* kvgrid = grids + ((br ^ 1) * NB + b) * HWC;
    const int2 rc = *reinterpret_cast<const int2*>(qc + (size_t)(b * NV + n) * 2);

    const int drs[9] = {0, -1, 1, 0, -1, 1, 0, -1, 1};
    const int dcs[9] = {0, 0, 0, 1, 1, 1, -1, -1, -1};
    int v[9];
    int mask = 0;
#pragma unroll
    for (int k = 0; k < 9; ++k) {
        int rr = rc.x + drs[k], cc = rc.y + dcs[k];
        bool valid = ((unsigned)rr < HH) & ((unsigned)cc < WW);
        int raw = kvgrid[valid ? rr * WW + cc : 0];
        int id = valid ? raw : -1;
        mask |= (int)(id >= 0) << k;
        v[k] = id > 0 ? id : 0;
    }
    int4* np = reinterpret_cast<int4*>(nbr + (size_t)q * 12);
    np[0] = make_int4(v[0], v[1], v[2], v[3]);
    np[1] = make_int4(v[4], v[5], v[6], v[7]);
    np[2] = make_int4(v[8], mask, 0, 0);
}

// ---------------------------------------------------------------------------
// K3b: slim attention core. 32 lanes per query, 2 queries per lane-group.
// One dependent round trip (KV gather); scores via DPP; writes o to res buf.
// ---------------------------------------------------------------------------
__launch_bounds__(256)
__global__ void k_attn(const int* __restrict__ nbr, const float* __restrict__ Qbuf,
                       const float* __restrict__ KV,
                       const float* __restrict__ b_qkv1, const float* __restrict__ b_qkv2,
                       float* __restrict__ obuf) {
    const int g = threadIdx.x >> 5;
    const int j = threadIdx.x & 31;
    const int q0 = (blockIdx.x * 8 + g) * 2;   // even; q0,q0+1 share br and b
    const int br  = (q0 >= NB * NV) ? 1 : 0;
    const int rem = q0 - br * NB * NV;
    const int bb  = rem / NV;
    const float* KVb  = KV + ((size_t)br * NB + bb) * (size_t)NV * 64;
    const float* bqkv = br ? b_qkv2 : b_qkv1;

    // batched nbr + Q loads (uniform addr per group -> broadcast requests)
    int4 a0[2], a1[2], a2[2];
#pragma unroll
    for (int u = 0; u < 2; ++u) {
        const int4* np = reinterpret_cast<const int4*>(nbr + (size_t)(q0 + u) * 12);
        a0[u] = np[0]; a1[u] = np[1]; a2[u] = np[2];
    }
    float Qv[2];
#pragma unroll
    for (int u = 0; u < 2; ++u) Qv[u] = Qbuf[(size_t)(q0 + u) * 32 + j];
    const float bk = bqkv[32 + j], bv = bqkv[64 + j];

    // batched KV gathers (the single dependent round trip)
    float2 kv[2][9];
#pragma unroll
    for (int u = 0; u < 2; ++u) {
        int id[9] = {a0[u].x, a0[u].y, a0[u].z, a0[u].w,
                     a1[u].x, a1[u].y, a1[u].z, a1[u].w, a2[u].x};
#pragma unroll
        for (int k = 0; k < 9; ++k)
            kv[u][k] = *reinterpret_cast<const float2*>(KVb + (size_t)id[k] * 64 + j * 2);
    }

    // scores + softmax + weighted V
#pragma unroll
    for (int u = 0; u < 2; ++u) {
        const int mask = a2[u].y;
        float sc[9];
#pragma unroll
        for (int k = 0; k < 9; ++k) {
            float kk = ((mask >> k) & 1) ? kv[u][k].x : bk;
            sc[k] = red16(Qv[u] * kk) * 0.25f;  // 1/sqrt(HD=16)
        }
        float m = sc[0];
#pragma unroll
        for (int k = 1; k < 9; ++k) m = fmaxf(m, sc[k]);
        float sum = 0.f, o = 0.f;
#pragma unroll
        for (int k = 0; k < 9; ++k) {
            float e = __expf(sc[k] - m);
            float vv = ((mask >> k) & 1) ? kv[u][k].y : bv;
            sum += e;
            o += e * vv;
        }
        obuf[(size_t)(q0 + u) * 32 + j] = o / sum;
    }
}

// ---------------------------------------------------------------------------
// K3c: out-projection + residual, in place on the o/res buffer.
// blockIdx.y = branch (weights hoisted out of the row loop).
// Each half-wave reads its full row before writing one element: in-place safe.
// ---------------------------------------------------------------------------
__launch_bounds__(256)
__global__ void k_outproj(const float* __restrict__ li_feats, const float* __restrict__ ra_feats,
                          const float* __restrict__ w_out1, const float* __restrict__ b_out1,
                          const float* __restrict__ w_out2, const float* __restrict__ b_out2,
                          float* __restrict__ res) {
    const int br   = blockIdx.y;
    const int lane = threadIdx.x & 63;
    const int j    = lane & 31;
    const int h    = lane >> 5;
    const float* wout = br ? w_out2 : w_out1;
    const float* qf   = br ? ra_feats : li_feats;
    float4 wr[8];
#pragma unroll
    for (int i = 0; i < 8; ++i) wr[i] = ld4(wout + j * 32 + i * 4);
    const float bo = (br ? b_out2 : b_out1)[j];

    float* rb = res + (size_t)br * NB * NV * 32;
    int wave   = blockIdx.x * (blockDim.x >> 6) + (threadIdx.x >> 6);
    int stride = gridDim.x * (blockDim.x >> 6);
    for (int pr = wave; pr < NB * NV / 2; pr += stride) {
        int row = pr * 2 + h;
        const float* op = rb + (size_t)row * 32;
        float acc = bo;
#pragma unroll
        for (int i = 0; i < 8; ++i) {
            float4 ov = ld4(op + i * 4);   // broadcast within half-wave
            float4 w = wr[i];
            acc += w.x * ov.x + w.y * ov.y + w.z * ov.z + w.w * ov.w;
        }
        float qv = qf[(size_t)row * 32 + j];
        rb[(size_t)row * 32 + j] = qv + acc;
    }
}

// ---------------------------------------------------------------------------
// K4: densify (inverted scatter). One thread per output cell; writes all 32
// channel planes coalesced, gathers the 128B res row (or zeros).
// ---------------------------------------------------------------------------
__launch_bounds__(256)
__global__ void k_densify(const int* __restrict__ grids, const float* __restrict__ res,
                          float* __restrict__ out) {
    int t = blockIdx.x * 256 + threadIdx.x;  // 0 .. NQ*... (2*NB*HWC-1)
    int plane = t >> 18;                     // (br*NB + b)
    int s = t & (HWC - 1);
    int gidx = grids[t];                     // query grid (set==branch)
    float4 v[8];
    if (gidx >= 0) {
        const float* rp = res + ((size_t)plane * NV + gidx) * 32;
#pragma unroll
        for (int i = 0; i < 8; ++i) v[i] = ld4(rp + i * 4);
    } else {
#pragma unroll
        for (int i = 0; i < 8; ++i) v[i] = make_float4(0.f, 0.f, 0.f, 0.f);
    }
    float* ob = out + (size_t)plane * 32 * HWC + s;
#pragma unroll
    for (int i = 0; i < 8; ++i) {
        ob[(size_t)(4 * i + 0) * HWC] = v[i].x;
        ob[(size_t)(4 * i + 1) * HWC] = v[i].y;
        ob[(size_t)(4 * i + 2) * HWC] = v[i].z;
        ob[(size_t)(4 * i + 3) * HWC] = v[i].w;
    }
}

// ---------------------------------------------------------------------------
extern "C" void kernel_launch(void* const* d_in, const int* in_sizes, int n_in,
                              void* d_out, int out_size, void* d_ws, size_t ws_size,
                              hipStream_t stream) {
    const float* li_feats = (const float*)d_in[0];
    const int*   li_coors = (const int*)d_in[1];
    const float* ra_feats = (const float*)d_in[2];
    const int*   ra_coors = (const int*)d_in[3];
    const float* w_qkv1 = (const float*)d_in[4];
    const float* b_qkv1 = (const float*)d_in[5];
    const float* w_out1 = (const float*)d_in[6];
    const float* b_out1 = (const float*)d_in[7];
    const float* w_qkv2 = (const float*)d_in[8];
    const float* b_qkv2 = (const float*)d_in[9];
    const float* w_out2 = (const float*)d_in[10];
    const float* b_out2 = (const float*)d_in[11];
    float* out = (float*)d_out;

    char* ws = (char*)d_ws;
    size_t off = 0;
    int*   grids = (int*)(ws + off);   off += (size_t)2 * NB * HWC * 4;   // 8 MB
    float* KV    = (float*)(ws + off); off += (size_t)NQ * 64 * 4;        // 102.4 MB
    float* res   = (float*)(ws + off); off += (size_t)NQ * 32 * 4;        // 51.2 MB (o, then res in-place)
    float* Qbuf  = (float*)(ws + off); off += (size_t)NQ * 32 * 4;        // 51.2 MB
    int*   nbr   = (int*)(ws + off);   off += (size_t)NQ * 12 * 4;        // 19.2 MB

    hipMemsetAsync(grids, 0xFF, (size_t)2 * NB * HWC * 4, stream);  // all -1

    k_grid<<<(NQ + 255) / 256, 256, 0, stream>>>(li_coors, ra_coors, grids);

    k_proj<<<1024, 256, 0, stream>>>(li_feats, ra_feats,
                                     w_qkv1, b_qkv1, w_qkv2, b_qkv2, KV);

    k_qproj<<<1024, 256, 0, stream>>>(li_feats, ra_feats,
                                      w_qkv1, b_qkv1, w_qkv2, b_qkv2, Qbuf);

    k_nbr<<<(NQ + 255) / 256, 256, 0, stream>>>(li_coors, ra_coors, grids, nbr);

    k_attn<<<NQ / 16, 256, 0, stream>>>(nbr, Qbuf, KV, b_qkv1, b_qkv2, res);

    k_outproj<<<dim3(512, 2), 256, 0, stream>>>(li_feats, ra_feats,
                                                w_out1, b_out1, w_out2, b_out2, res);

    k_densify<<<(2 * NB * HWC) / 256, 256, 0, stream>>>(grids, res, out);
}

// Round 5
// 412.400 us; speedup vs baseline: 2.3017x; 1.1590x over previous
//
#include <hip/hip_runtime.h>

#define HH 512
#define WW 512
#define HWC (HH * WW)          // 262144 = 2^18
#define NV 50000
#define NB 4
#define NR (NB * NV)           // 200000 rows per branch
#define NQ (2 * NR)            // 400000 total queries

static __device__ __forceinline__ float4 ld4(const float* p) {
    return *reinterpret_cast<const float4*>(p);
}

// Sum across each 16-lane row via DPP (VALU pipe, no LDS).
static __device__ __forceinline__ float red16(float x) {
    float t;
    t = __int_as_float(__builtin_amdgcn_update_dpp(0, __float_as_int(x), 0xB1, 0xF, 0xF, true));  // quad_perm(1,0,3,2)
    x += t;
    t = __int_as_float(__builtin_amdgcn_update_dpp(0, __float_as_int(x), 0x4E, 0xF, 0xF, true));  // quad_perm(2,3,0,1)
    x += t;
    t = __int_as_float(__builtin_amdgcn_update_dpp(0, __float_as_int(x), 0x141, 0xF, 0xF, true)); // row_half_mirror
    x += t;
    t = __int_as_float(__builtin_amdgcn_update_dpp(0, __float_as_int(x), 0x140, 0xF, 0xF, true)); // row_mirror
    x += t;
    return x;
}

// ---------------------------------------------------------------------------
// K1: scatter voxel indices into dense coord->index grids
// grids layout: [set(0=li,1=ra)][b][HWC], pre-filled with -1
// ---------------------------------------------------------------------------
__global__ void k_grid(const int* __restrict__ li_coors, const int* __restrict__ ra_coors,
                       int* __restrict__ grids) {
    int t = blockIdx.x * blockDim.x + threadIdx.x;
    if (t >= NQ) return;
    int set = t / NR;
    int r2 = t - set * NR;
    int b = r2 / NV;
    int n = r2 - b * NV;
    const int* co = (set == 0 ? li_coors : ra_coors) + (size_t)(b * NV + n) * 2;
    grids[(set * NB + b) * HWC + co[0] * WW + co[1]] = n;
}

// ---------------------------------------------------------------------------
// K2: combined projection. blockIdx.y = f (0=li_feats, 1=ra_feats).
// Each feats row is read ONCE and produces:
//   Q row (32)  -> Qbuf[branch f]     with wq  of w_qkv(f?2:1)
//   K|V row (64)-> KV  [branch f^1]   with wk,wv of w_qkv(f?1:2)
// One row per thread; transposed weights broadcast from LDS; ILP=32.
// KV layout: [br][row][j][2]  ([0]=K_j, [1]=V_j).
// ---------------------------------------------------------------------------
__launch_bounds__(256)
__global__ void k_proj_all(const float* __restrict__ li_feats, const float* __restrict__ ra_feats,
                           const float* __restrict__ w_qkv1, const float* __restrict__ b_qkv1,
                           const float* __restrict__ w_qkv2, const float* __restrict__ b_qkv2,
                           float* __restrict__ Qbuf, float* __restrict__ KV) {
    const int f = blockIdx.y;
    const float* feats = f ? ra_feats : li_feats;
    const float* wq_g  = f ? w_qkv2 : w_qkv1;   // queries of branch f
    const float* bq_g  = f ? b_qkv2 : b_qkv1;
    const float* wkv_g = f ? w_qkv1 : w_qkv2;   // keys/values consumed by branch f^1
    const float* bkv_g = f ? b_qkv1 : b_qkv2;

    __shared__ float wqT[1024], wkT[1024], wvT[1024];
    __shared__ float bqL[32], bkL[32], bvL[32];
    for (int l = threadIdx.x; l < 1024; l += 256) {
        int c = l >> 5, i = l & 31;
        wqT[i * 32 + c] = wq_g[c * 32 + i];
        wkT[i * 32 + c] = wkv_g[(32 + c) * 32 + i];
        wvT[i * 32 + c] = wkv_g[(64 + c) * 32 + i];
    }
    if (threadIdx.x < 32) {
        bqL[threadIdx.x] = bq_g[threadIdx.x];
        bkL[threadIdx.x] = bkv_g[32 + threadIdx.x];
        bvL[threadIdx.x] = bkv_g[64 + threadIdx.x];
    }
    __syncthreads();

    const int row = blockIdx.x * 256 + threadIdx.x;
    if (row >= NR) return;
    const float* rp = feats + (size_t)row * 32;
    float rr[32];
#pragma unroll
    for (int i8 = 0; i8 < 8; ++i8) {
        float4 t = ld4(rp + i8 * 4);
        rr[i8 * 4 + 0] = t.x; rr[i8 * 4 + 1] = t.y;
        rr[i8 * 4 + 2] = t.z; rr[i8 * 4 + 3] = t.w;
    }

    // ---- Q chunk ------------------------------------------------------
    {
        float acc[32];
#pragma unroll
        for (int c = 0; c < 32; ++c) acc[c] = bqL[c];
#pragma unroll
        for (int i = 0; i < 32; ++i) {
            float v = rr[i];
#pragma unroll
            for (int c4 = 0; c4 < 8; ++c4) {
                float4 w = *reinterpret_cast<const float4*>(&wqT[i * 32 + c4 * 4]);
                acc[c4 * 4 + 0] += v * w.x;
                acc[c4 * 4 + 1] += v * w.y;
                acc[c4 * 4 + 2] += v * w.z;
                acc[c4 * 4 + 3] += v * w.w;
            }
        }
        float* Qb = Qbuf + (size_t)f * NR * 32 + (size_t)row * 32;
#pragma unroll
        for (int c4 = 0; c4 < 8; ++c4)
            *reinterpret_cast<float4*>(Qb + c4 * 4) =
                make_float4(acc[c4 * 4 + 0], acc[c4 * 4 + 1], acc[c4 * 4 + 2], acc[c4 * 4 + 3]);
    }

    // ---- K|V chunk ----------------------------------------------------
    {
        float ak[32], av[32];
#pragma unroll
        for (int c = 0; c < 32; ++c) { ak[c] = bkL[c]; av[c] = bvL[c]; }
#pragma unroll
        for (int i = 0; i < 32; ++i) {
            float v = rr[i];
#pragma unroll
            for (int c4 = 0; c4 < 8; ++c4) {
                float4 wk = *reinterpret_cast<const float4*>(&wkT[i * 32 + c4 * 4]);
                float4 wv = *reinterpret_cast<const float4*>(&wvT[i * 32 + c4 * 4]);
                ak[c4 * 4 + 0] += v * wk.x; av[c4 * 4 + 0] += v * wv.x;
                ak[c4 * 4 + 1] += v * wk.y; av[c4 * 4 + 1] += v * wv.y;
                ak[c4 * 4 + 2] += v * wk.z; av[c4 * 4 + 2] += v * wv.z;
                ak[c4 * 4 + 3] += v * wk.w; av[c4 * 4 + 3] += v * wv.w;
            }
        }
        float* KVr = KV + (size_t)(f ^ 1) * NR * 64 + (size_t)row * 64;
#pragma unroll
        for (int c2 = 0; c2 < 16; ++c2)
            *reinterpret_cast<float4*>(KVr + c2 * 4) =
                make_float4(ak[c2 * 2], av[c2 * 2], ak[c2 * 2 + 1], av[c2 * 2 + 1]);
    }
}

// ---------------------------------------------------------------------------
// K3a: neighbor resolve. 1 thread per query; 9 independent grid loads.
// Writes [q][12]: idx0..8 (clamped), mask, pad, pad.
// ---------------------------------------------------------------------------
__global__ void k_nbr(const int* __restrict__ li_coors, const int* __restrict__ ra_coors,
                      const int* __restrict__ grids, int* __restrict__ nbr) {
    int q = blockIdx.x * 256 + threadIdx.x;
    if (q >= NQ) return;
    int br  = (q >= NR) ? 1 : 0;
    int rem = q - br * NR;
    int b   = rem / NV;
    const int* qc = br ? ra_coors : li_coors;
    const int* kvgrid = grids + ((br ^ 1) * NB + b) * HWC;
    const int2 rc = *reinterpret_cast<const int2*>(qc + (size_t)rem * 2);

    const int drs[9] = {0, -1, 1, 0, -1, 1, 0, -1, 1};
    const int dcs[9] = {0, 0, 0, 1, 1, 1, -1, -1, -1};
    int v[9];
    int mask = 0;
#pragma unroll
    for (int k = 0; k < 9; ++k) {
        int rr = rc.x + drs[k], cc = rc.y + dcs[k];
        bool valid = ((unsigned)rr < HH) & ((unsigned)cc < WW);
        int raw = kvgrid[valid ? rr * WW + cc : 0];
        int id = valid ? raw : -1;
        mask |= (int)(id >= 0) << k;
        v[k] = id > 0 ? id : 0;
    }
    int4* np = reinterpret_cast<int4*>(nbr + (size_t)q * 12);
    np[0] = make_int4(v[0], v[1], v[2], v[3]);
    np[1] = make_int4(v[4], v[5], v[6], v[7]);
    np[2] = make_int4(v[8], mask, 0, 0);
}

// ---------------------------------------------------------------------------
// K3b: slim attention core. 32 lanes per query, 2 queries per lane-group.
// One dependent round trip (KV gather); scores via DPP; writes o to res buf.
// ---------------------------------------------------------------------------
__launch_bounds__(256)
__global__ void k_attn(const int* __restrict__ nbr, const float* __restrict__ Qbuf,
                       const float* __restrict__ KV,
                       const float* __restrict__ b_qkv1, const float* __restrict__ b_qkv2,
                       float* __restrict__ obuf) {
    const int g = threadIdx.x >> 5;
    const int j = threadIdx.x & 31;
    const int q0 = (blockIdx.x * 8 + g) * 2;   // even; q0,q0+1 share br and b
    const int br  = (q0 >= NR) ? 1 : 0;
    const int rem = q0 - br * NR;
    const float* KVb  = KV + (size_t)br * NR * 64;
    const float* bqkv = br ? b_qkv2 : b_qkv1;
    const int bb = rem / NV;
    const float* KVbb = KVb + (size_t)bb * NV * 64;

    int4 a0[2], a1[2], a2[2];
#pragma unroll
    for (int u = 0; u < 2; ++u) {
        const int4* np = reinterpret_cast<const int4*>(nbr + (size_t)(q0 + u) * 12);
        a0[u] = np[0]; a1[u] = np[1]; a2[u] = np[2];
    }
    float Qv[2];
#pragma unroll
    for (int u = 0; u < 2; ++u) Qv[u] = Qbuf[(size_t)(q0 + u) * 32 + j];
    const float bk = bqkv[32 + j], bv = bqkv[64 + j];

    float2 kv[2][9];
#pragma unroll
    for (int u = 0; u < 2; ++u) {
        int id[9] = {a0[u].x, a0[u].y, a0[u].z, a0[u].w,
                     a1[u].x, a1[u].y, a1[u].z, a1[u].w, a2[u].x};
#pragma unroll
        for (int k = 0; k < 9; ++k)
            kv[u][k] = *reinterpret_cast<const float2*>(KVbb + (size_t)id[k] * 64 + j * 2);
    }

#pragma unroll
    for (int u = 0; u < 2; ++u) {
        const int mask = a2[u].y;
        float sc[9];
#pragma unroll
        for (int k = 0; k < 9; ++k) {
            float kk = ((mask >> k) & 1) ? kv[u][k].x : bk;
            sc[k] = red16(Qv[u] * kk) * 0.25f;  // 1/sqrt(HD=16)
        }
        float m = sc[0];
#pragma unroll
        for (int k = 1; k < 9; ++k) m = fmaxf(m, sc[k]);
        float sum = 0.f, o = 0.f;
#pragma unroll
        for (int k = 0; k < 9; ++k) {
            float e = __expf(sc[k] - m);
            float vv = ((mask >> k) & 1) ? kv[u][k].y : bv;
            sum += e;
            o += e * vv;
        }
        obuf[(size_t)(q0 + u) * 32 + j] = o / sum;
    }
}

// ---------------------------------------------------------------------------
// K3c: out-projection + residual, in place. One row per thread, both
// branches' transposed w_out in LDS, ILP=32.
// ---------------------------------------------------------------------------
__launch_bounds__(256)
__global__ void k_outproj(const float* __restrict__ li_feats, const float* __restrict__ ra_feats,
                          const float* __restrict__ w_out1, const float* __restrict__ b_out1,
                          const float* __restrict__ w_out2, const float* __restrict__ b_out2,
                          float* __restrict__ res) {
    __shared__ float woT[2][1024];
    __shared__ float boL[2][32];
    for (int l = threadIdx.x; l < 1024; l += 256) {
        int c = l >> 5, i = l & 31;
        woT[0][i * 32 + c] = w_out1[c * 32 + i];
        woT[1][i * 32 + c] = w_out2[c * 32 + i];
    }
    if (threadIdx.x < 32) {
        boL[0][threadIdx.x] = b_out1[threadIdx.x];
        boL[1][threadIdx.x] = b_out2[threadIdx.x];
    }
    __syncthreads();

    const int q = blockIdx.x * 256 + threadIdx.x;
    if (q >= NQ) return;
    const int br = (q >= NR) ? 1 : 0;
    const float* feats = br ? ra_feats : li_feats;
    const float* frow = feats + (size_t)(q - br * NR) * 32;
    float* orow = res + (size_t)q * 32;
    const float* wT = woT[br];

    float rr[32];
#pragma unroll
    for (int i8 = 0; i8 < 8; ++i8) {
        float4 t = ld4(orow + i8 * 4);
        rr[i8 * 4 + 0] = t.x; rr[i8 * 4 + 1] = t.y;
        rr[i8 * 4 + 2] = t.z; rr[i8 * 4 + 3] = t.w;
    }
    float acc[32];
#pragma unroll
    for (int c = 0; c < 32; ++c) acc[c] = boL[br][c];
#pragma unroll
    for (int i = 0; i < 32; ++i) {
        float v = rr[i];
#pragma unroll
        for (int c4 = 0; c4 < 8; ++c4) {
            float4 w = *reinterpret_cast<const float4*>(&wT[i * 32 + c4 * 4]);
            acc[c4 * 4 + 0] += v * w.x;
            acc[c4 * 4 + 1] += v * w.y;
            acc[c4 * 4 + 2] += v * w.z;
            acc[c4 * 4 + 3] += v * w.w;
        }
    }
#pragma unroll
    for (int c4 = 0; c4 < 8; ++c4) {
        float4 fv = ld4(frow + c4 * 4);
        *reinterpret_cast<float4*>(orow + c4 * 4) =
            make_float4(acc[c4 * 4 + 0] + fv.x, acc[c4 * 4 + 1] + fv.y,
                        acc[c4 * 4 + 2] + fv.z, acc[c4 * 4 + 3] + fv.w);
    }
}

// ---------------------------------------------------------------------------
// K4: densify (inverted scatter). One thread per output cell; writes all 32
// channel planes coalesced, gathers the 128B res row (or zeros).
// ---------------------------------------------------------------------------
__launch_bounds__(256)
__global__ void k_densify(const int* __restrict__ grids, const float* __restrict__ res,
                          float* __restrict__ out) {
    int t = blockIdx.x * 256 + threadIdx.x;  // 0 .. 2*NB*HWC-1
    int plane = t >> 18;                     // (br*NB + b)
    int s = t & (HWC - 1);
    int gidx = grids[t];                     // query grid (set==branch)
    float4 v[8];
    if (gidx >= 0) {
        const float* rp = res + ((size_t)plane * NV + gidx) * 32;
#pragma unroll
        for (int i = 0; i < 8; ++i) v[i] = ld4(rp + i * 4);
    } else {
#pragma unroll
        for (int i = 0; i < 8; ++i) v[i] = make_float4(0.f, 0.f, 0.f, 0.f);
    }
    float* ob = out + (size_t)plane * 32 * HWC + s;
#pragma unroll
    for (int i = 0; i < 8; ++i) {
        ob[(size_t)(4 * i + 0) * HWC] = v[i].x;
        ob[(size_t)(4 * i + 1) * HWC] = v[i].y;
        ob[(size_t)(4 * i + 2) * HWC] = v[i].z;
        ob[(size_t)(4 * i + 3) * HWC] = v[i].w;
    }
}

// ---------------------------------------------------------------------------
extern "C" void kernel_launch(void* const* d_in, const int* in_sizes, int n_in,
                              void* d_out, int out_size, void* d_ws, size_t ws_size,
                              hipStream_t stream) {
    const float* li_feats = (const float*)d_in[0];
    const int*   li_coors = (const int*)d_in[1];
    const float* ra_feats = (const float*)d_in[2];
    const int*   ra_coors = (const int*)d_in[3];
    const float* w_qkv1 = (const float*)d_in[4];
    const float* b_qkv1 = (const float*)d_in[5];
    const float* w_out1 = (const float*)d_in[6];
    const float* b_out1 = (const float*)d_in[7];
    const float* w_qkv2 = (const float*)d_in[8];
    const float* b_qkv2 = (const float*)d_in[9];
    const float* w_out2 = (const float*)d_in[10];
    const float* b_out2 = (const float*)d_in[11];
    float* out = (float*)d_out;

    char* ws = (char*)d_ws;
    size_t off = 0;
    int*   grids = (int*)(ws + off);   off += (size_t)2 * NB * HWC * 4;   // 8 MB
    float* KV    = (float*)(ws + off); off += (size_t)NQ * 64 * 4;        // 102.4 MB
    float* res   = (float*)(ws + off); off += (size_t)NQ * 32 * 4;        // 51.2 MB (o, then res in-place)
    float* Qbuf  = (float*)(ws + off); off += (size_t)NQ * 32 * 4;        // 51.2 MB
    int*   nbr   = (int*)(ws + off);   off += (size_t)NQ * 12 * 4;        // 19.2 MB

    hipMemsetAsync(grids, 0xFF, (size_t)2 * NB * HWC * 4, stream);  // all -1

    k_grid<<<(NQ + 255) / 256, 256, 0, stream>>>(li_coors, ra_coors, grids);

    k_proj_all<<<dim3((NR + 255) / 256, 2), 256, 0, stream>>>(
        li_feats, ra_feats, w_qkv1, b_qkv1, w_qkv2, b_qkv2, Qbuf, KV);

    k_nbr<<<(NQ + 255) / 256, 256, 0, stream>>>(li_coors, ra_coors, grids, nbr);

    k_attn<<<NQ / 16, 256, 0, stream>>>(nbr, Qbuf, KV, b_qkv1, b_qkv2, res);

    k_outproj<<<(NQ + 255) / 256, 256, 0, stream>>>(li_feats, ra_feats,
                                                    w_out1, b_out1, w_out2, b_out2, res);

    k_densify<<<(2 * NB * HWC) / 256, 256, 0, stream>>>(grids, res, out);
}

// Round 6
// 376.675 us; speedup vs baseline: 2.5200x; 1.0948x over previous
//
#include <hip/hip_runtime.h>

#define HH 512
#define WW 512
#define HWC (HH * WW)          // 262144 = 2^18
#define NV 50000
#define NB 4
#define NR (NB * NV)           // 200000 rows per branch
#define NQ (2 * NR)            // 400000 total queries

static __device__ __forceinline__ float4 ld4(const float* p) {
    return *reinterpret_cast<const float4*>(p);
}

// Sum across each 16-lane row via DPP (VALU pipe, no LDS).
static __device__ __forceinline__ float red16(float x) {
    float t;
    t = __int_as_float(__builtin_amdgcn_update_dpp(0, __float_as_int(x), 0xB1, 0xF, 0xF, true));  // quad_perm(1,0,3,2)
    x += t;
    t = __int_as_float(__builtin_amdgcn_update_dpp(0, __float_as_int(x), 0x4E, 0xF, 0xF, true));  // quad_perm(2,3,0,1)
    x += t;
    t = __int_as_float(__builtin_amdgcn_update_dpp(0, __float_as_int(x), 0x141, 0xF, 0xF, true)); // row_half_mirror
    x += t;
    t = __int_as_float(__builtin_amdgcn_update_dpp(0, __float_as_int(x), 0x140, 0xF, 0xF, true)); // row_mirror
    x += t;
    return x;
}

// ---------------------------------------------------------------------------
// K1: scatter voxel indices into dense coord->index grids
// grids layout: [set(0=li,1=ra)][b][HWC], pre-filled with -1
// ---------------------------------------------------------------------------
__global__ void k_grid(const int* __restrict__ li_coors, const int* __restrict__ ra_coors,
                       int* __restrict__ grids) {
    int t = blockIdx.x * blockDim.x + threadIdx.x;
    if (t >= NQ) return;
    int set = t / NR;
    int r2 = t - set * NR;
    int b = r2 / NV;
    int n = r2 - b * NV;
    const int* co = (set == 0 ? li_coors : ra_coors) + (size_t)(b * NV + n) * 2;
    grids[(set * NB + b) * HWC + co[0] * WW + co[1]] = n;
}

// ---------------------------------------------------------------------------
// K2: combined projection, wave-structured. blockIdx.y = f (feats tensor).
// Each WAVE processes 2 rows per iter: 64 lanes coalesced-load rows r0,r0+1
// into a 64-float LDS tile; each 32-lane half broadcast-reads its own row
// (uniform ds_read_b128, 2 addrs/wave = free) and computes output column
// j = lane&31 for Q (branch f) and K,V (branch f^1) with weights in VGPRs.
// KV layout: [br][row][j][2]  ([0]=K_j, [1]=V_j).
// ---------------------------------------------------------------------------
__launch_bounds__(256)
__global__ void k_proj_all(const float* __restrict__ li_feats, const float* __restrict__ ra_feats,
                           const float* __restrict__ w_qkv1, const float* __restrict__ b_qkv1,
                           const float* __restrict__ w_qkv2, const float* __restrict__ b_qkv2,
                           float* __restrict__ Qbuf, float* __restrict__ KV) {
    const int f = blockIdx.y;
    const float* feats = f ? ra_feats : li_feats;
    const float* wq_g  = f ? w_qkv2 : w_qkv1;   // queries of branch f
    const float* bq_g  = f ? b_qkv2 : b_qkv1;
    const float* wkv_g = f ? w_qkv1 : w_qkv2;   // keys/values consumed by branch f^1
    const float* bkv_g = f ? b_qkv1 : b_qkv2;

    __shared__ float xs[4][64];
    const int wave = threadIdx.x >> 6;
    const int l    = threadIdx.x & 63;
    const int h    = l >> 5;         // which row of the pair
    const int j    = l & 31;         // output column

    // per-lane weight rows (row j of each weight matrix) in VGPRs
    float4 wq[8], wk[8], wv[8];
#pragma unroll
    for (int i = 0; i < 8; ++i) {
        wq[i] = ld4(wq_g  + j * 32 + i * 4);
        wk[i] = ld4(wkv_g + (32 + j) * 32 + i * 4);
        wv[i] = ld4(wkv_g + (64 + j) * 32 + i * 4);
    }
    const float bq = bq_g[j], bk = bkv_g[32 + j], bv = bkv_g[64 + j];

    float* Qb  = Qbuf + (size_t)f * NR * 32;
    float* KVb = KV + (size_t)(f ^ 1) * NR * 64;

    const int gw = blockIdx.x * 4 + wave;          // global wave id
    const int gs = gridDim.x * 4;                  // wave stride
    for (int r0 = gw * 2; r0 < NR; r0 += gs * 2) {
        xs[wave][l] = feats[(size_t)r0 * 32 + l];  // rows r0, r0+1 coalesced
        const float* xp = &xs[wave][h * 32];
        float aq = bq, ak = bk, av = bv;
#pragma unroll
        for (int i = 0; i < 8; ++i) {
            float4 x = *reinterpret_cast<const float4*>(xp + i * 4);  // broadcast
            aq += x.x * wq[i].x + x.y * wq[i].y + x.z * wq[i].z + x.w * wq[i].w;
            ak += x.x * wk[i].x + x.y * wk[i].y + x.z * wk[i].z + x.w * wk[i].w;
            av += x.x * wv[i].x + x.y * wv[i].y + x.z * wv[i].z + x.w * wv[i].w;
        }
        const int row = r0 + h;
        Qb[(size_t)row * 32 + j] = aq;
        *reinterpret_cast<float2*>(KVb + (size_t)row * 64 + j * 2) = make_float2(ak, av);
    }
}

// ---------------------------------------------------------------------------
// K3a: neighbor resolve. 1 thread per query; 9 independent grid loads.
// Writes [q][12]: idx0..8 (clamped), mask, pad, pad.
// ---------------------------------------------------------------------------
__global__ void k_nbr(const int* __restrict__ li_coors, const int* __restrict__ ra_coors,
                      const int* __restrict__ grids, int* __restrict__ nbr) {
    int q = blockIdx.x * 256 + threadIdx.x;
    if (q >= NQ) return;
    int br  = (q >= NR) ? 1 : 0;
    int rem = q - br * NR;
    int b   = rem / NV;
    const int* qc = br ? ra_coors : li_coors;
    const int* kvgrid = grids + ((br ^ 1) * NB + b) * HWC;
    const int2 rc = *reinterpret_cast<const int2*>(qc + (size_t)rem * 2);

    const int drs[9] = {0, -1, 1, 0, -1, 1, 0, -1, 1};
    const int dcs[9] = {0, 0, 0, 1, 1, 1, -1, -1, -1};
    int v[9];
    int mask = 0;
#pragma unroll
    for (int k = 0; k < 9; ++k) {
        int rr = rc.x + drs[k], cc = rc.y + dcs[k];
        bool valid = ((unsigned)rr < HH) & ((unsigned)cc < WW);
        int raw = kvgrid[valid ? rr * WW + cc : 0];
        int id = valid ? raw : -1;
        mask |= (int)(id >= 0) << k;
        v[k] = id > 0 ? id : 0;
    }
    int4* np = reinterpret_cast<int4*>(nbr + (size_t)q * 12);
    np[0] = make_int4(v[0], v[1], v[2], v[3]);
    np[1] = make_int4(v[4], v[5], v[6], v[7]);
    np[2] = make_int4(v[8], mask, 0, 0);
}

// ---------------------------------------------------------------------------
// K3b: slim attention core. 32 lanes per query, 2 queries per lane-group.
// One dependent round trip (KV gather); scores via DPP; writes o to res buf.
// ---------------------------------------------------------------------------
__launch_bounds__(256)
__global__ void k_attn(const int* __restrict__ nbr, const float* __restrict__ Qbuf,
                       const float* __restrict__ KV,
                       const float* __restrict__ b_qkv1, const float* __restrict__ b_qkv2,
                       float* __restrict__ obuf) {
    const int g = threadIdx.x >> 5;
    const int j = threadIdx.x & 31;
    const int q0 = (blockIdx.x * 8 + g) * 2;   // even; q0,q0+1 share br and b
    const int br  = (q0 >= NR) ? 1 : 0;
    const int rem = q0 - br * NR;
    const float* KVb  = KV + (size_t)br * NR * 64;
    const float* bqkv = br ? b_qkv2 : b_qkv1;
    const int bb = rem / NV;
    const float* KVbb = KVb + (size_t)bb * NV * 64;

    int4 a0[2], a1[2], a2[2];
#pragma unroll
    for (int u = 0; u < 2; ++u) {
        const int4* np = reinterpret_cast<const int4*>(nbr + (size_t)(q0 + u) * 12);
        a0[u] = np[0]; a1[u] = np[1]; a2[u] = np[2];
    }
    float Qv[2];
#pragma unroll
    for (int u = 0; u < 2; ++u) Qv[u] = Qbuf[(size_t)(q0 + u) * 32 + j];
    const float bk = bqkv[32 + j], bv = bqkv[64 + j];

    float2 kv[2][9];
#pragma unroll
    for (int u = 0; u < 2; ++u) {
        int id[9] = {a0[u].x, a0[u].y, a0[u].z, a0[u].w,
                     a1[u].x, a1[u].y, a1[u].z, a1[u].w, a2[u].x};
#pragma unroll
        for (int k = 0; k < 9; ++k)
            kv[u][k] = *reinterpret_cast<const float2*>(KVbb + (size_t)id[k] * 64 + j * 2);
    }

#pragma unroll
    for (int u = 0; u < 2; ++u) {
        const int mask = a2[u].y;
        float sc[9];
#pragma unroll
        for (int k = 0; k < 9; ++k) {
            float kk = ((mask >> k) & 1) ? kv[u][k].x : bk;
            sc[k] = red16(Qv[u] * kk) * 0.25f;  // 1/sqrt(HD=16)
        }
        float m = sc[0];
#pragma unroll
        for (int k = 1; k < 9; ++k) m = fmaxf(m, sc[k]);
        float sum = 0.f, o = 0.f;
#pragma unroll
        for (int k = 0; k < 9; ++k) {
            float e = __expf(sc[k] - m);
            float vv = ((mask >> k) & 1) ? kv[u][k].y : bv;
            sum += e;
            o += e * vv;
        }
        obuf[(size_t)(q0 + u) * 32 + j] = o / sum;
    }
}

// ---------------------------------------------------------------------------
// K3c: out-projection + residual, in place, wave-structured like k_proj_all.
// blockIdx.y = branch. Wave reads rows r0,r0+1 fully (LDS tile) before
// writing them back: in-place safe within the wave.
// ---------------------------------------------------------------------------
__launch_bounds__(256)
__global__ void k_outproj(const float* __restrict__ li_feats, const float* __restrict__ ra_feats,
                          const float* __restrict__ w_out1, const float* __restrict__ b_out1,
                          const float* __restrict__ w_out2, const float* __restrict__ b_out2,
                          float* __restrict__ res) {
    const int br = blockIdx.y;
    const float* wout = br ? w_out2 : w_out1;
    const float* qf   = br ? ra_feats : li_feats;

    __shared__ float xs[4][64];
    const int wave = threadIdx.x >> 6;
    const int l    = threadIdx.x & 63;
    const int h    = l >> 5;
    const int j    = l & 31;

    float4 wo[8];
#pragma unroll
    for (int i = 0; i < 8; ++i) wo[i] = ld4(wout + j * 32 + i * 4);
    const float bo = (br ? b_out2 : b_out1)[j];

    float* rb = res + (size_t)br * NR * 32;

    const int gw = blockIdx.x * 4 + wave;
    const int gs = gridDim.x * 4;
    for (int r0 = gw * 2; r0 < NR; r0 += gs * 2) {
        xs[wave][l] = rb[(size_t)r0 * 32 + l];     // o rows r0,r0+1 coalesced
        const float* xp = &xs[wave][h * 32];
        float acc = bo;
#pragma unroll
        for (int i = 0; i < 8; ++i) {
            float4 x = *reinterpret_cast<const float4*>(xp + i * 4);  // broadcast
            acc += x.x * wo[i].x + x.y * wo[i].y + x.z * wo[i].z + x.w * wo[i].w;
        }
        const int row = r0 + h;
        float qv = qf[(size_t)row * 32 + j];
        rb[(size_t)row * 32 + j] = qv + acc;
    }
}

// ---------------------------------------------------------------------------
// K4: densify (inverted scatter). One thread per output cell; writes all 32
// channel planes coalesced, gathers the 128B res row (or zeros).
// ---------------------------------------------------------------------------
__launch_bounds__(256)
__global__ void k_densify(const int* __restrict__ grids, const float* __restrict__ res,
                          float* __restrict__ out) {
    int t = blockIdx.x * 256 + threadIdx.x;  // 0 .. 2*NB*HWC-1
    int plane = t >> 18;                     // (br*NB + b)
    int s = t & (HWC - 1);
    int gidx = grids[t];                     // query grid (set==branch)
    float4 v[8];
    if (gidx >= 0) {
        const float* rp = res + ((size_t)plane * NV + gidx) * 32;
#pragma unroll
        for (int i = 0; i < 8; ++i) v[i] = ld4(rp + i * 4);
    } else {
#pragma unroll
        for (int i = 0; i < 8; ++i) v[i] = make_float4(0.f, 0.f, 0.f, 0.f);
    }
    float* ob = out + (size_t)plane * 32 * HWC + s;
#pragma unroll
    for (int i = 0; i < 8; ++i) {
        ob[(size_t)(4 * i + 0) * HWC] = v[i].x;
        ob[(size_t)(4 * i + 1) * HWC] = v[i].y;
        ob[(size_t)(4 * i + 2) * HWC] = v[i].z;
        ob[(size_t)(4 * i + 3) * HWC] = v[i].w;
    }
}

// ---------------------------------------------------------------------------
extern "C" void kernel_launch(void* const* d_in, const int* in_sizes, int n_in,
                              void* d_out, int out_size, void* d_ws, size_t ws_size,
                              hipStream_t stream) {
    const float* li_feats = (const float*)d_in[0];
    const int*   li_coors = (const int*)d_in[1];
    const float* ra_feats = (const float*)d_in[2];
    const int*   ra_coors = (const int*)d_in[3];
    const float* w_qkv1 = (const float*)d_in[4];
    const float* b_qkv1 = (const float*)d_in[5];
    const float* w_out1 = (const float*)d_in[6];
    const float* b_out1 = (const float*)d_in[7];
    const float* w_qkv2 = (const float*)d_in[8];
    const float* b_qkv2 = (const float*)d_in[9];
    const float* w_out2 = (const float*)d_in[10];
    const float* b_out2 = (const float*)d_in[11];
    float* out = (float*)d_out;

    char* ws = (char*)d_ws;
    size_t off = 0;
    int*   grids = (int*)(ws + off);   off += (size_t)2 * NB * HWC * 4;   // 8 MB
    float* KV    = (float*)(ws + off); off += (size_t)NQ * 64 * 4;        // 102.4 MB
    float* res   = (float*)(ws + off); off += (size_t)NQ * 32 * 4;        // 51.2 MB (o, then res in-place)
    float* Qbuf  = (float*)(ws + off); off += (size_t)NQ * 32 * 4;        // 51.2 MB
    int*   nbr   = (int*)(ws + off);   off += (size_t)NQ * 12 * 4;        // 19.2 MB

    hipMemsetAsync(grids, 0xFF, (size_t)2 * NB * HWC * 4, stream);  // all -1

    k_grid<<<(NQ + 255) / 256, 256, 0, stream>>>(li_coors, ra_coors, grids);

    k_proj_all<<<dim3(3200, 2), 256, 0, stream>>>(
        li_feats, ra_feats, w_qkv1, b_qkv1, w_qkv2, b_qkv2, Qbuf, KV);

    k_nbr<<<(NQ + 255) / 256, 256, 0, stream>>>(li_coors, ra_coors, grids, nbr);

    k_attn<<<NQ / 16, 256, 0, stream>>>(nbr, Qbuf, KV, b_qkv1, b_qkv2, res);

    k_outproj<<<dim3(3200, 2), 256, 0, stream>>>(li_feats, ra_feats,
                                                 w_out1, b_out1, w_out2, b_out2, res);

    k_densify<<<(2 * NB * HWC) / 256, 256, 0, stream>>>(grids, res, out);
}